// Round 6
// baseline (201.602 us; speedup 1.0000x reference)
//
#include <hip/hip_runtime.h>

// LinearCRF: mean_b( logZ_b - gold_b ), B=8192, L=1024, S=3.
// Scaled linear-domain forward: lane owns a 16-step chunk, builds the 3x3
// transfer-matrix product in linear space with exact power-of-2 renorm;
// 6-stage ordered shfl_xor butterfly composes 64 chunks per wave
// (1 wave = 1 sequence). Gold score fused.
// R9: attack all three suspects of the 66us invariant at once, with
// mechanisms that don't conflict:
//  (1) MLP without VGPRs: em staged via 12x global_load_lds DMA per wave
//      (coalesced, vmcnt-counted, zero dest regs). R7/R8 proved hipcc
//      will NOT keep a 20-load register burst live (VGPR stuck at 60
//      despite launch_bounds(256,3) + sched_barrier).
//  (2) I$: body fully rolled (R6's bit-exact rolled structure, ~2KB).
//  (3) cache: em reads coalesced via DMA; LDS consume is cache-immune;
//      mask/tags = 8 one-line-per-lane streaming loads, packed to 2
//      scalars immediately (tags 2b, mask 1b) so they can't be sunk.
// LDS 48KiB/block -> 3 blocks/CU = 12 waves/CU. ds_read_b128 at 192B
// lane stride ~4x bank-aliased but only 12 reads/wave -> hides under VALU.

#define LOG2E 1.4426950408889634f
#define LN2   0.6931471805599453f

constexpr int B = 8192;
constexpr int L = 1024;
constexpr int SEQS_PER_BLOCK = 4;   // 4 waves of 64 per block

__device__ __forceinline__ float fexp2(float x) { return __builtin_amdgcn_exp2f(x); }
__device__ __forceinline__ float flog2(float x) { return __builtin_amdgcn_logf(x); }

__device__ __forceinline__ float f4get(const float4& v, int c) {
  return c == 0 ? v.x : (c == 1 ? v.y : (c == 2 ? v.z : v.w));
}

__device__ __forceinline__ float mux3(float x0, float x1, float x2, int i) {
  return (i == 0) ? x0 : ((i == 1) ? x1 : x2);
}

__device__ __forceinline__ unsigned packmask4(const float4& v) {
  return (unsigned)(v.x > 0.f) | ((unsigned)(v.y > 0.f) << 1) |
         ((unsigned)(v.z > 0.f) << 2) | ((unsigned)(v.w > 0.f) << 3);
}
__device__ __forceinline__ unsigned packtag4(const int4& v) {
  return (unsigned)(v.x | (v.y << 2) | (v.z << 4) | (v.w << 6));
}

// Exact power-of-2 renormalization: P *= 2^-ex, scale += ex.
__device__ __forceinline__ void renorm3(float* __restrict__ P, float& scale) {
  float m = P[0];
  #pragma unroll
  for (int e = 1; e < 9; ++e) m = fmaxf(m, P[e]);
  int ex;
  (void)frexpf(m, &ex);
  #pragma unroll
  for (int e = 0; e < 9; ++e) P[e] = ldexpf(P[e], -ex);
  scale += (float)ex;
}

__global__ __launch_bounds__(256, 3) void crf_main(
    const float* __restrict__ em, const float* __restrict__ mask,
    const float* __restrict__ trans, const int* __restrict__ tags,
    float* __restrict__ out) {
  const int lane = threadIdx.x & 63;
  const int wid = threadIdx.x >> 6;
  const int b = blockIdx.x * SEQS_PER_BLOCK + wid;

  // Per-wave em staging: 768 float4 = 12KiB per wave, linear layout
  // (global float4 index == LDS slot index; DMA writes base + lane*16).
  __shared__ float4 sEm[SEQS_PER_BLOCK][768];   // 48 KiB
  __shared__ float sT2[12];                     // 9 used: trans * log2(e)
  __shared__ float red[SEQS_PER_BLOCK];
  if (threadIdx.x < 9) sT2[threadIdx.x] = trans[threadIdx.x] * LOG2E;

  const float4* emG = (const float4*)em + (size_t)b * 768;
  const float4* mkp = (const float4*)(mask + (size_t)b * L) + lane * 4;
  const int4*   tgp = (const int4*)(tags + (size_t)b * L) + lane * 4;

  // ---- mask/tag streaming loads first (1 full line per lane per instr) ----
  const float4 M0 = mkp[0], M1 = mkp[1], M2 = mkp[2], M3 = mkp[3];
  const int4   G0 = tgp[0], G1 = tgp[1], G2 = tgp[2], G3 = tgp[3];

  // ---- em: 12 coalesced DMA chunks, global->LDS, no dest VGPRs ----
  #pragma unroll
  for (int i = 0; i < 12; ++i) {
    __builtin_amdgcn_global_load_lds(
        (const __attribute__((address_space(1))) void*)(emG + 64 * i + lane),
        (__attribute__((address_space(3))) void*)(&sEm[wid][64 * i]),
        16, 0, 0);
  }

  // ---- pack mask/tags to 2 scalars (forces consumption at the top) ----
  const unsigned mpack = packmask4(M0) | (packmask4(M1) << 4) |
                         (packmask4(M2) << 8) | (packmask4(M3) << 12);
  const unsigned tpack = packtag4(G0) | (packtag4(G1) << 8) |
                         (packtag4(G2) << 16) | (packtag4(G3) << 24);

  // Transitions in linear form (uniform -> scalar loads + 9 exp2),
  // computed while DMAs are in flight.
  float tk[9];
  #pragma unroll
  for (int e = 0; e < 9; ++e) tk[e] = fexp2(trans[e] * LOG2E);

  // Drains vmcnt (DMA completion for our own LDS region) AND publishes sT2.
  __syncthreads();

  float P[9] = {1.f, 0.f, 0.f, 0.f, 1.f, 0.f, 0.f, 0.f, 1.f};
  float scale = 0.f, gold = 0.f;
  float a0 = 0.f, a1 = 0.f, a2 = 0.f;   // chunk-step-0 linear emissions
  float e0_sel = 0.f, mk0 = 0.f;        // deferred chunk-step-0 gold term
  int tag0 = 0, prev = 0;

  const float4* myEm = &sEm[wid][lane * 12];

  // ---- rolled main loop: 4 quads x 4 steps; em from LDS ----
  #pragma unroll 1
  for (int q = 0; q < 4; ++q) {
    const float4 E0 = myEm[3 * q + 0];
    const float4 E1 = myEm[3 * q + 1];
    const float4 E2 = myEm[3 * q + 2];

    #pragma unroll
    for (int k = 0; k < 4; ++k) {
      // static element->register muxing (k is compile-time after unroll)
      const int i0 = 3 * k + 0, i1 = 3 * k + 1, i2 = 3 * k + 2;
      const float ev0 = f4get(i0 < 4 ? E0 : (i0 < 8 ? E1 : E2), i0 & 3) * LOG2E;
      const float ev1 = f4get(i1 < 4 ? E0 : (i1 < 8 ? E1 : E2), i1 & 3) * LOG2E;
      const float ev2 = f4get(i2 < 4 ? E0 : (i2 < 8 ? E1 : E2), i2 & 3) * LOG2E;
      const float m   = ((mpack >> (4 * q + k)) & 1u) ? 1.f : 0.f;
      const int   cur = (int)((tpack >> (8 * q + 2 * k)) & 3u);

      // ---- gold score (log2 domain); trans score via LDS LUT ----
      const float e = mux3(ev0, ev1, ev2, cur);
      if (k == 0 && q == 0) {
        e0_sel = e; mk0 = m; tag0 = cur;   // deferred: needs prev lane's tag
      } else {
        gold = fmaf(sT2[3 * prev + cur] + e, m, gold);
      }
      prev = cur;

      // ---- matrix step (linear domain): M = act ? tk.*w : I ----
      const float w0 = fexp2(ev0);
      const float w1 = fexp2(ev1);
      const float w2 = fexp2(ev2);
      if (k == 0 && q == 0) { a0 = w0; a1 = w1; a2 = w2; }
      const bool first = (k == 0) && (q == 0);
      const bool act = (m > 0.f) && !(first && lane == 0);  // t=0 is alpha0
      const float gg = act ? 1.f : 0.f;
      const float c1 = 1.f - gg;
      const float u0 = w0 * gg, u1 = w1 * gg, u2 = w2 * gg;
      float M[9];
      M[0] = fmaf(tk[0], u0, c1); M[1] = tk[1] * u1;           M[2] = tk[2] * u2;
      M[3] = tk[3] * u0;          M[4] = fmaf(tk[4], u1, c1);  M[5] = tk[5] * u2;
      M[6] = tk[6] * u0;          M[7] = tk[7] * u1;           M[8] = fmaf(tk[8], u2, c1);
      // in-place P <- P*M (row i of result depends only on row i of P)
      #pragma unroll
      for (int i = 0; i < 3; ++i) {
        const float p0 = P[3 * i + 0], p1 = P[3 * i + 1], p2 = P[3 * i + 2];
        P[3 * i + 0] = p0 * M[0] + p1 * M[3] + p2 * M[6];
        P[3 * i + 1] = p0 * M[1] + p1 * M[4] + p2 * M[7];
        P[3 * i + 2] = p0 * M[2] + p1 * M[5] + p2 * M[8];
      }
    }
    if (q & 1) renorm3(P, scale);  // after s==7 and s==15: bound fp32 range
  }

  // ---- deferred chunk-step-0 gold term (needs previous lane's last tag) ----
  const int prevLast = __shfl_up(prev, 1);     // prev == tag15 here
  const float t0 = sT2[3 * prevLast + tag0];
  gold = fmaf((lane == 0 ? 0.f : t0) + e0_sel, mk0, gold);

  // ---- rolled ordered butterfly combine + fused gold reduce ----
  // (entries <= 3^6 = 729 growth per stage chain: no renorm needed)
  #pragma unroll 1
  for (int d = 1; d < 64; d <<= 1) {
    float o[9];
    #pragma unroll
    for (int e = 0; e < 9; ++e) o[e] = __shfl_xor(P[e], d, 64);
    const float osc = __shfl_xor(scale, d, 64);
    gold += __shfl_xor(gold, d, 64);
    const bool later = (lane & d) != 0;  // self covers the later time segment
    float A[9], Bm[9];
    #pragma unroll
    for (int e = 0; e < 9; ++e) {
      A[e]  = later ? o[e] : P[e];
      Bm[e] = later ? P[e] : o[e];
    }
    #pragma unroll
    for (int i = 0; i < 3; ++i) {
      const float p0 = A[3 * i + 0], p1 = A[3 * i + 1], p2 = A[3 * i + 2];
      P[3 * i + 0] = p0 * Bm[0] + p1 * Bm[3] + p2 * Bm[6];
      P[3 * i + 1] = p0 * Bm[1] + p1 * Bm[4] + p2 * Bm[7];
      P[3 * i + 2] = p0 * Bm[2] + p1 * Bm[5] + p2 * Bm[8];
    }
    scale += osc;
  }

  // ---- finalize + block reduce + atomic ----
  if (lane == 0) {
    const float z = a0 * (P[0] + P[1] + P[2]) +
                    a1 * (P[3] + P[4] + P[5]) +
                    a2 * (P[6] + P[7] + P[8]);
    red[wid] = LN2 * (scale + flog2(z) - gold);
  }
  __syncthreads();
  if (threadIdx.x == 0) {
    const float s = red[0] + red[1] + red[2] + red[3];
    atomicAdd(out, s * (1.0f / (float)B));
  }
}

extern "C" void kernel_launch(void* const* d_in, const int* in_sizes, int n_in,
                              void* d_out, int out_size, void* d_ws, size_t ws_size,
                              hipStream_t stream) {
  const float* em    = (const float*)d_in[0];
  const float* mask  = (const float*)d_in[1];
  const float* trans = (const float*)d_in[2];
  const int*   tags  = (const int*)d_in[3];
  float* out = (float*)d_out;

  hipMemsetAsync(out, 0, sizeof(float), stream);  // atomic accumulator init
  crf_main<<<B / SEQS_PER_BLOCK, 256, 0, stream>>>(em, mask, trans, tags, out);
}

// Round 7
// 197.426 us; speedup vs baseline: 1.0212x; 1.0212x over previous
//
#include <hip/hip_runtime.h>

// LinearCRF: mean_b( logZ_b - gold_b ), B=8192, L=1024, S=3.
// Scaled linear-domain forward: lane owns a 16-step chunk, builds the 3x3
// transfer-matrix product in linear space with exact power-of-2 renorm;
// 6-stage ordered shfl_xor butterfly composes 64 chunks per wave
// (1 wave = 1 sequence). Gold score fused.
// R10: output path is the ONLY change vs the 66us R3 kernel. Theory: the
// invariant ~45us across R3/R4/R7/R9 is an ATOMIC-DRAIN TAIL -- 2048
// blocks all finish ~simultaneously (all 32 waves/CU resident from t=0)
// and their single-address atomicAdd(out) bursts serialize at the
// coherence point (~50-100cyc apiece = 40-85us) while every CU holds a
// zombie wave. Time-averaged counters match exactly: active ~20us at
// ~100% occ / ~90% VALU duty + idle tail => measured occ 31%, VALUBusy
// 27%. Fix: per-block partial -> d_ws[blockIdx.x] (plain store), tiny
// second kernel reduces 2048 floats and writes the mean. No atomic, no
// memset anywhere.

#define LOG2E 1.4426950408889634f
#define LN2   0.6931471805599453f

constexpr int B = 8192;
constexpr int L = 1024;
constexpr int SEQS_PER_BLOCK = 4;   // 4 waves of 64 per block
constexpr int NBLK = B / SEQS_PER_BLOCK;  // 2048 partials

__device__ __forceinline__ float fexp2(float x) { return __builtin_amdgcn_exp2f(x); }
__device__ __forceinline__ float flog2(float x) { return __builtin_amdgcn_logf(x); }

__device__ __forceinline__ float f4get(const float4& v, int c) {
  return c == 0 ? v.x : (c == 1 ? v.y : (c == 2 ? v.z : v.w));
}
__device__ __forceinline__ int i4get(const int4& v, int c) {
  return c == 0 ? v.x : (c == 1 ? v.y : (c == 2 ? v.z : v.w));
}

__device__ __forceinline__ float mux3(float x0, float x1, float x2, int i) {
  return (i == 0) ? x0 : ((i == 1) ? x1 : x2);
}
// transitions[p][c] via cndmask chain (no dynamic register indexing)
__device__ __forceinline__ float trmux(const float* __restrict__ T2, int p, int c) {
  const float r0 = mux3(T2[0], T2[1], T2[2], c);
  const float r1 = mux3(T2[3], T2[4], T2[5], c);
  const float r2 = mux3(T2[6], T2[7], T2[8], c);
  return mux3(r0, r1, r2, p);
}

__device__ __forceinline__ void matmul3(float* __restrict__ D,
                                        const float* __restrict__ A,
                                        const float* __restrict__ Bm) {
  #pragma unroll
  for (int i = 0; i < 3; ++i)
    #pragma unroll
    for (int j = 0; j < 3; ++j)
      D[i * 3 + j] = A[i * 3 + 0] * Bm[0 * 3 + j] +
                     A[i * 3 + 1] * Bm[1 * 3 + j] +
                     A[i * 3 + 2] * Bm[2 * 3 + j];
}

// Exact power-of-2 renormalization: P *= 2^-ex, scale += ex.
__device__ __forceinline__ void renorm3(float* __restrict__ P, float& scale) {
  float m = P[0];
  #pragma unroll
  for (int e = 1; e < 9; ++e) m = fmaxf(m, P[e]);
  int ex;
  (void)frexpf(m, &ex);
  #pragma unroll
  for (int e = 0; e < 9; ++e) P[e] = ldexpf(P[e], -ex);
  scale += (float)ex;
}

__global__ __launch_bounds__(256, 4) void crf_main(
    const float* __restrict__ em, const float* __restrict__ mask,
    const float* __restrict__ trans, const int* __restrict__ tags,
    float* __restrict__ ws) {
  const int lane = threadIdx.x & 63;
  const int wid = threadIdx.x >> 6;
  const int b = blockIdx.x * SEQS_PER_BLOCK + wid;

  const float4* em4 = (const float4*)(em + (size_t)b * (L * 3)) + lane * 12;
  const float4* mk4 = (const float4*)(mask + (size_t)b * L) + lane * 4;
  const int4*   tg4 = (const int4*)(tags + (size_t)b * L) + lane * 4;

  // ---- issue ALL global loads up front: ONE latency burst per wave ----
  float4 E[12];
  #pragma unroll
  for (int u = 0; u < 12; ++u) E[u] = em4[u];
  float4 MK[4];
  #pragma unroll
  for (int u = 0; u < 4; ++u) MK[u] = mk4[u];
  int4 TG[4];
  #pragma unroll
  for (int u = 0; u < 4; ++u) TG[u] = tg4[u];

  // Transitions: log2 domain + linear form (uniform -> scalar loads).
  float T2[9], tk[9];
  #pragma unroll
  for (int e = 0; e < 9; ++e) {
    T2[e] = trans[e] * LOG2E;
    tk[e] = fexp2(T2[e]);
  }

  float P[9] = {1.f, 0.f, 0.f, 0.f, 1.f, 0.f, 0.f, 0.f, 1.f};
  float scale = 0.f, gold = 0.f;
  float a0 = 0.f, a1 = 0.f, a2 = 0.f;   // step-0 linear emissions (lane 0)
  float e0_sel = 0.f, mk0 = 0.f;        // deferred step-0 gold term
  int tag0 = 0, prev = 0;

  #pragma unroll
  for (int s = 0; s < 16; ++s) {
    const float ev0 = f4get(E[(3 * s + 0) >> 2], (3 * s + 0) & 3) * LOG2E;
    const float ev1 = f4get(E[(3 * s + 1) >> 2], (3 * s + 1) & 3) * LOG2E;
    const float ev2 = f4get(E[(3 * s + 2) >> 2], (3 * s + 2) & 3) * LOG2E;
    const float m   = f4get(MK[s >> 2], s & 3);
    const int   cur = i4get(TG[s >> 2], s & 3);

    // ---- gold score (log2 domain) ----
    const float e = mux3(ev0, ev1, ev2, cur);
    if (s == 0) {
      e0_sel = e; mk0 = m; tag0 = cur;   // cross-lane prev tag fixed up later
    } else {
      gold = fmaf(trmux(T2, prev, cur) + e, m, gold);
    }
    prev = cur;

    // ---- matrix step (linear domain): M = act ? tk.*w : I ----
    const float w0 = fexp2(ev0);
    const float w1 = fexp2(ev1);
    const float w2 = fexp2(ev2);
    if (s == 0) { a0 = w0; a1 = w1; a2 = w2; }
    const bool act = (m > 0.f) && !(s == 0 && lane == 0);  // t=0 is alpha0
    const float g  = act ? 1.f : 0.f;
    const float c1 = 1.f - g;
    const float u0 = w0 * g, u1 = w1 * g, u2 = w2 * g;
    float M[9];
    M[0] = fmaf(tk[0], u0, c1); M[1] = tk[1] * u1;           M[2] = tk[2] * u2;
    M[3] = tk[3] * u0;          M[4] = fmaf(tk[4], u1, c1);  M[5] = tk[5] * u2;
    M[6] = tk[6] * u0;          M[7] = tk[7] * u1;           M[8] = fmaf(tk[8], u2, c1);
    float N[9];
    matmul3(N, P, M);
    #pragma unroll
    for (int e2 = 0; e2 < 9; ++e2) P[e2] = N[e2];

    if (s == 7 || s == 15) renorm3(P, scale);  // bound fp32 range
  }

  // ---- deferred step-0 gold term (needs previous lane's last tag) ----
  const int prevLast = __shfl_up(prev, 1);
  if (lane == 0) gold = fmaf(e0_sel, mk0, gold);
  else           gold = fmaf(trmux(T2, prevLast, tag0) + e0_sel, mk0, gold);
  #pragma unroll
  for (int d = 1; d < 64; d <<= 1) gold += __shfl_xor(gold, d, 64);

  // ---- ordered butterfly combine (entries <= 3^6 = 729: no renorm needed) ----
  #pragma unroll
  for (int d = 1; d < 64; d <<= 1) {
    float o[9];
    #pragma unroll
    for (int e = 0; e < 9; ++e) o[e] = __shfl_xor(P[e], d, 64);
    const float osc = __shfl_xor(scale, d, 64);
    const bool later = (lane & d) != 0;  // self covers the later time segment
    float A[9], Bm[9];
    #pragma unroll
    for (int e = 0; e < 9; ++e) {
      A[e]  = later ? o[e] : P[e];
      Bm[e] = later ? P[e] : o[e];
    }
    float N[9];
    matmul3(N, A, Bm);
    #pragma unroll
    for (int e = 0; e < 9; ++e) P[e] = N[e];
    scale += osc;
  }

  // ---- finalize + block partial -> workspace (NO atomic) ----
  __shared__ float red[SEQS_PER_BLOCK];
  if (lane == 0) {
    const float z = a0 * (P[0] + P[1] + P[2]) +
                    a1 * (P[3] + P[4] + P[5]) +
                    a2 * (P[6] + P[7] + P[8]);
    red[wid] = LN2 * (scale + flog2(z) - gold);
  }
  __syncthreads();
  if (threadIdx.x == 0) {
    ws[blockIdx.x] = red[0] + red[1] + red[2] + red[3];
  }
}

// Reduce 2048 block partials -> mean. One block, no atomics.
__global__ __launch_bounds__(256) void crf_reduce(
    const float* __restrict__ ws, float* __restrict__ out) {
  const int t = threadIdx.x;
  const float4* w4 = (const float4*)ws;
  float4 v0 = w4[t];            // 256 threads x 2 float4 = 2048 floats
  float4 v1 = w4[256 + t];
  float s = (v0.x + v0.y) + (v0.z + v0.w) + (v1.x + v1.y) + (v1.z + v1.w);
  #pragma unroll
  for (int d = 1; d < 64; d <<= 1) s += __shfl_xor(s, d, 64);
  __shared__ float red[4];
  if ((t & 63) == 0) red[t >> 6] = s;
  __syncthreads();
  if (t == 0) out[0] = (red[0] + red[1] + red[2] + red[3]) * (1.0f / (float)B);
}

extern "C" void kernel_launch(void* const* d_in, const int* in_sizes, int n_in,
                              void* d_out, int out_size, void* d_ws, size_t ws_size,
                              hipStream_t stream) {
  const float* em    = (const float*)d_in[0];
  const float* mask  = (const float*)d_in[1];
  const float* trans = (const float*)d_in[2];
  const int*   tags  = (const int*)d_in[3];
  float* out = (float*)d_out;
  float* ws  = (float*)d_ws;

  crf_main<<<NBLK, 256, 0, stream>>>(em, mask, trans, tags, ws);
  crf_reduce<<<1, 256, 0, stream>>>(ws, out);
}